// Round 6
// baseline (163.953 us; speedup 1.0000x reference)
//
#include <hip/hip_runtime.h>

// IGN 2->2 dense layer, N=4, M=256, D=32, S=32, fp32.
// out[n,i,j,s] = sum_d (C10[d,s]*in[n,i,j,d] + C11[d,s]*in[n,j,i,d])
//              + RW[n,i,s] + CW[n,j,s] + (i==j)*DW[n,i,s]

#define NN 4
#define MM 256
#define DD 32
#define SS 32

// ---- workspace layout (float offsets) ----
#define WS_ROWS   0          // [N*M*D]  32768
#define WS_DIAG   32768      // [N*M*D]  32768
#define WS_COLSP  65536      // [4][N*M*D] 131072  cols partials (i-quarters)
#define WS_RW     196608     // [N*M*S] 32768
#define WS_CW     229376     // [N*M*S] 32768
#define WS_DW     262144     // [N*M*S] 32768
#define WS_SD     294912     // [N*D] = 128  (atomics; memset to 0 first)
#define WS_TOT    295040     // [N*D] = 128  (atomics; memset to 0 first)
#define WS_CPACK  295168     // [15][D*S] = 15360  plane-major packed coeffs
// end: 310528 floats = 1242112 bytes

// Kernel 1. blocks [0,128): cols partials; [128,1152): rows+diag+sd/tot;
// block 1152: coeff pack.
__global__ __launch_bounds__(256) void k_reduce(const float* __restrict__ in,
                                                const float* __restrict__ coeffs,
                                                float* __restrict__ ws) {
    int blk = blockIdx.x;
    int t = threadIdx.x;
    if (blk < 128) {
        // cols[n,j,d] over an i-quarter. Tile: 64 i x 32 j x 32 d.
        // thread owns (jl = t>>3, d4 = t&7); per-i wave reads contiguous 1KB.
        int n = blk >> 5;
        int rem = blk & 31;
        int jb = rem >> 2, ih = rem & 3;
        int i0 = ih * 64, j0 = jb * 32;
        int jl = t >> 3, d4 = t & 7;
        const float4* base = (const float4*)in;
        size_t idx0 = ((size_t)(n * MM + i0) * MM + (j0 + jl)) * 8 + d4;
        float4 a = {0.f, 0.f, 0.f, 0.f};
        #pragma unroll 8
        for (int i = 0; i < 64; ++i) {
            float4 v = base[idx0 + (size_t)i * MM * 8];
            a.x += v.x; a.y += v.y; a.z += v.z; a.w += v.w;
        }
        ((float4*)(ws + WS_COLSP))[(size_t)ih * 8192 + (n * MM + j0 + jl) * 8 + d4] = a;
    } else if (blk < 128 + NN * MM) {
        // rows[nm,d] = sum_j in[nm,j,d]; also diag, sd, tot.
        int nm = blk - 128;            // n*M + i
        int n = nm >> 8;
        int ii = nm & 255;
        int d4 = t & 7, jg = t >> 3;   // 32 j-groups x 8 d4
        const float4* base = (const float4*)(in + (size_t)nm * MM * DD);
        float4 a = {0.f, 0.f, 0.f, 0.f};
        #pragma unroll
        for (int k = 0; k < 8; ++k) {
            float4 v = base[(jg * 8 + k) * 8 + d4];
            a.x += v.x; a.y += v.y; a.z += v.z; a.w += v.w;
        }
        __shared__ float4 red[256];
        red[t] = a;
        __syncthreads();
        if (t < 8) {
            float4 s = {0.f, 0.f, 0.f, 0.f};
            #pragma unroll 8
            for (int g = 0; g < 32; ++g) {
                float4 v = red[g * 8 + t];
                s.x += v.x; s.y += v.y; s.z += v.z; s.w += v.w;
            }
            ((float4*)(ws + WS_ROWS))[nm * 8 + t] = s;
            float4 dv = ((const float4*)in)[((size_t)nm * MM + ii) * 8 + t];
            ((float4*)(ws + WS_DIAG))[nm * 8 + t] = dv;
            atomicAdd(ws + WS_TOT + n * DD + t * 4 + 0, s.x);
            atomicAdd(ws + WS_TOT + n * DD + t * 4 + 1, s.y);
            atomicAdd(ws + WS_TOT + n * DD + t * 4 + 2, s.z);
            atomicAdd(ws + WS_TOT + n * DD + t * 4 + 3, s.w);
            atomicAdd(ws + WS_SD + n * DD + t * 4 + 0, dv.x);
            atomicAdd(ws + WS_SD + n * DD + t * 4 + 1, dv.y);
            atomicAdd(ws + WS_SD + n * DD + t * 4 + 2, dv.z);
            atomicAdd(ws + WS_SD + n * DD + t * 4 + 3, dv.w);
        }
    } else {
        // pack coeffs [D*S,15] -> [15][D*S]
        for (int idx = t; idx < 15 * DD * SS; idx += 256) {
            int plane = idx >> 10;
            int ds = idx & 1023;
            ws[WS_CPACK + plane * (DD * SS) + ds] = coeffs[ds * 15 + plane];
        }
    }
}

// Kernel 2: RW/CW/DW.  grid = N*M*S/256 = 128 blocks; thread -> (n,i,s).
__global__ __launch_bounds__(256) void k_aux(const float* __restrict__ diag_bias,
                                             const float* __restrict__ all_bias,
                                             float* __restrict__ ws) {
    int idx = blockIdx.x * blockDim.x + threadIdx.x;   // over N*M*S
    int s = idx & 31;
    int nm = idx >> 5;                                  // n*M + i
    int n = nm >> 8;
    const float inv_m = 1.0f / MM;
    const float inv_m2 = inv_m * inv_m;
    float u = 0.f, v = 0.f, dgacc = 0.f, w = 0.f;
    for (int d = 0; d < DD; ++d) {
        const float* cp = ws + WS_CPACK + d * SS + s;   // plane stride 1024
        float r = ws[WS_ROWS + nm * DD + d];
        float cl = ws[WS_COLSP + 0 * 32768 + nm * DD + d]
                 + ws[WS_COLSP + 1 * 32768 + nm * DD + d]
                 + ws[WS_COLSP + 2 * 32768 + nm * DD + d]
                 + ws[WS_COLSP + 3 * 32768 + nm * DD + d];
        float dv = ws[WS_DIAG + nm * DD + d];
        float sdv = ws[WS_SD + n * DD + d];
        float totv = ws[WS_TOT + n * DD + d];
        // i-dependent, all j: op6 cols_i/m, op7 rows_i/m, op12 diag_i
        u += cp[5 * 1024] * cl * inv_m + cp[6 * 1024] * r * inv_m + cp[11 * 1024] * dv;
        // j-dependent: op8 cols_j/m, op9 rows_j/m, op13 diag_j
        v += cp[7 * 1024] * cl * inv_m + cp[8 * 1024] * r * inv_m + cp[12 * 1024] * dv;
        // diagonal-only: op1..op5
        dgacc += cp[0] * dv + cp[1 * 1024] * sdv * inv_m + cp[2 * 1024] * r * inv_m
               + cp[3 * 1024] * cl * inv_m + cp[4 * 1024] * totv * inv_m2;
        // constant: op14 sd/m, op15 tot/m^2
        w += cp[13 * 1024] * sdv * inv_m + cp[14 * 1024] * totv * inv_m2;
    }
    ws[WS_RW + idx] = u + w + all_bias[s];
    ws[WS_CW + idx] = v;
    ws[WS_DW + idx] = dgacc + diag_bias[s];
}

// Kernel 3: main.  grid = N*16*16 = 1024 blocks of 256; thread -> one (i,j).
// Load clusters pinned with sched_barrier(0) so all 16 A/B loads stay in flight.
__global__ __launch_bounds__(256) void k_main(const float* __restrict__ in,
                                              const float* __restrict__ ws,
                                              float* __restrict__ out) {
    int b = blockIdx.x;
    int tjb = b & 15;
    int tib = (b >> 4) & 15;
    int n = b >> 8;
    int tj = threadIdx.x & 15, ti = threadIdx.x >> 4;
    int i = tib * 16 + ti, j = tjb * 16 + tj;

    // cluster 1: RW/CW rows (8+8 dwordx4)
    const float4* rw = (const float4*)(ws + WS_RW + (n * MM + i) * SS);
    const float4* cw = (const float4*)(ws + WS_CW + (n * MM + j) * SS);
    float4 rv[8], cv[8];
    #pragma unroll
    for (int q = 0; q < 8; ++q) rv[q] = rw[q];
    #pragma unroll
    for (int q = 0; q < 8; ++q) cv[q] = cw[q];
    __builtin_amdgcn_sched_barrier(0);

    float acc[SS];
    #pragma unroll
    for (int q = 0; q < 8; ++q) {
        acc[q * 4 + 0] = rv[q].x + cv[q].x;
        acc[q * 4 + 1] = rv[q].y + cv[q].y;
        acc[q * 4 + 2] = rv[q].z + cv[q].z;
        acc[q * 4 + 3] = rv[q].w + cv[q].w;
    }
    if (i == j) {
        const float4* dw = (const float4*)(ws + WS_DW + (n * MM + i) * SS);
        #pragma unroll
        for (int q = 0; q < 8; ++q) {
            float4 dq = dw[q];
            acc[q * 4 + 0] += dq.x;
            acc[q * 4 + 1] += dq.y;
            acc[q * 4 + 2] += dq.z;
            acc[q * 4 + 3] += dq.w;
        }
    }

    // cluster 2: A/B inputs (8+8 dwordx4), all in flight before FMA phase
    const float4* A = (const float4*)(in + (((size_t)(n * MM + i)) * MM + j) * DD);
    const float4* B = (const float4*)(in + (((size_t)(n * MM + j)) * MM + i) * DD);
    float4 av[8], bv[8];
    #pragma unroll
    for (int q = 0; q < 8; ++q) av[q] = A[q];
    #pragma unroll
    for (int q = 0; q < 8; ++q) bv[q] = B[q];
    __builtin_amdgcn_sched_barrier(0);

    const float* c10 = ws + WS_CPACK + 9 * (DD * SS);    // uniform -> s_load
    const float* c11 = ws + WS_CPACK + 10 * (DD * SS);
    #pragma unroll
    for (int dq = 0; dq < 8; ++dq) {
        const float* ca = c10 + dq * 4 * SS;
        const float* cb = c11 + dq * 4 * SS;
        #pragma unroll
        for (int r = 0; r < 4; ++r) {
            float a = (r == 0) ? av[dq].x : (r == 1) ? av[dq].y : (r == 2) ? av[dq].z : av[dq].w;
            float bb = (r == 0) ? bv[dq].x : (r == 1) ? bv[dq].y : (r == 2) ? bv[dq].z : bv[dq].w;
            #pragma unroll
            for (int s = 0; s < SS; ++s) {
                acc[s] = fmaf(a, ca[r * SS + s], acc[s]);
                acc[s] = fmaf(bb, cb[r * SS + s], acc[s]);
            }
        }
    }

    float4* o = (float4*)(out + (((size_t)(n * MM + i)) * MM + j) * SS);
    #pragma unroll
    for (int q = 0; q < 8; ++q)
        o[q] = make_float4(acc[q * 4 + 0], acc[q * 4 + 1], acc[q * 4 + 2], acc[q * 4 + 3]);
}

extern "C" void kernel_launch(void* const* d_in, const int* in_sizes, int n_in,
                              void* d_out, int out_size, void* d_ws, size_t ws_size,
                              hipStream_t stream) {
    const float* in = (const float*)d_in[0];
    // d_in[1] = mask (all-ones, unused by the reference math)
    const float* coeffs = (const float*)d_in[2];
    const float* diag_bias = (const float*)d_in[3];
    const float* all_bias = (const float*)d_in[4];
    float* out = (float*)d_out;
    float* ws = (float*)d_ws;

    // zero the atomic accumulators sd/tot (256 floats)
    hipMemsetAsync((char*)d_ws + (size_t)WS_SD * 4, 0, 256 * sizeof(float), stream);
    k_reduce<<<128 + NN * MM + 1, 256, 0, stream>>>(in, coeffs, ws);
    k_aux<<<(NN * MM * SS) / 256, 256, 0, stream>>>(diag_bias, all_bias, ws);
    k_main<<<NN * 16 * 16, 256, 0, stream>>>(in, ws, out);
}

// Round 8
// 160.114 us; speedup vs baseline: 1.0240x; 1.0240x over previous
//
#include <hip/hip_runtime.h>

// IGN 2->2 dense layer, N=4, M=256, D=32, S=32, fp32.
// out[n,i,j,s] = sum_d (C10[d,s]*in[n,i,j,d] + C11[d,s]*in[n,j,i,d])
//              + RW[n,i,s] + CWt[n,s,j] + (i==j)*DW[n,i,s]

#define NN 4
#define MM 256
#define DD 32
#define SS 32

// ---- workspace layout (float offsets) ----
#define WS_COLS   0          // [N*M*D] 32768 (atomic target; memset)
#define WS_SD     32768      // [N*D]   128   (atomic; memset)
#define WS_TOT    32896      // [N*D]   128   (atomic; memset)
#define WS_ROWS   33024      // [N*M*D] 32768
#define WS_DIAG   65792      // [N*M*D] 32768
#define WS_RW     98560      // [N*M*S] 32768  (row-major: s_load in k_main)
#define WS_CWT    131328     // [N*S*M] 32768  (transposed: coalesced in k_main)
#define WS_DW     164096     // [N*M*S] 32768
#define WS_CPACK  196864     // [15][D*S] 15360
// end: 212224 floats = 848896 bytes

// k_rows: block per (n,i). rows[nm,d] = sum_j in[nm,j,d]; diag; sd/tot atomics.
__global__ __launch_bounds__(256) void k_rows(const float* __restrict__ in,
                                              float* __restrict__ ws) {
    int nm = blockIdx.x;              // n*M + i
    int n = nm >> 8;
    int ii = nm & 255;
    int t = threadIdx.x;
    const float4* base = (const float4*)(in + (size_t)nm * MM * DD);
    // f4 idx = t + k*256 -> (j = idx/8, d4 = idx%8); d4 = t&7 invariant over k.
    float4 a = {0.f, 0.f, 0.f, 0.f};
    #pragma unroll
    for (int k = 0; k < 8; ++k) {
        float4 v = base[t + k * 256];
        a.x += v.x; a.y += v.y; a.z += v.z; a.w += v.w;
    }
    __shared__ float4 red[256];
    red[t] = a;
    __syncthreads();
    if (t < 8) {
        float4 s = {0.f, 0.f, 0.f, 0.f};
        #pragma unroll 8
        for (int g = 0; g < 32; ++g) {       // sum groups with same d4
            float4 v = red[g * 8 + t];
            s.x += v.x; s.y += v.y; s.z += v.z; s.w += v.w;
        }
        ((float4*)(ws + WS_ROWS))[nm * 8 + t] = s;
        float4 dv = ((const float4*)in)[((size_t)nm * MM + ii) * 8 + t];
        ((float4*)(ws + WS_DIAG))[nm * 8 + t] = dv;
        atomicAdd(ws + WS_TOT + n * DD + t * 4 + 0, s.x);
        atomicAdd(ws + WS_TOT + n * DD + t * 4 + 1, s.y);
        atomicAdd(ws + WS_TOT + n * DD + t * 4 + 2, s.z);
        atomicAdd(ws + WS_TOT + n * DD + t * 4 + 3, s.w);
        atomicAdd(ws + WS_SD + n * DD + t * 4 + 0, dv.x);
        atomicAdd(ws + WS_SD + n * DD + t * 4 + 1, dv.y);
        atomicAdd(ws + WS_SD + n * DD + t * 4 + 2, dv.z);
        atomicAdd(ws + WS_SD + n * DD + t * 4 + 3, dv.w);
    }
}

// k_cols: blocks 0..255 -> (n, jb, ic): cols partial over 32 i's, atomic add.
// block 256: coeff pack [D*S,15] -> [15][D*S].
__global__ __launch_bounds__(256) void k_cols(const float* __restrict__ in,
                                              const float* __restrict__ coeffs,
                                              float* __restrict__ ws) {
    int b = blockIdx.x;
    int t = threadIdx.x;
    if (b < 256) {
        int n = b >> 6, jb = (b >> 3) & 7, ic = b & 7;
        int i0 = ic * 32, j0 = jb * 32;
        // slice (n, i, j0:j0+32, :) is 4KB contiguous; thread t owns f4 #t.
        const float4* base = (const float4*)in
            + ((size_t)(n * MM + i0) * MM + j0) * 8 + t;
        float4 a0 = {0,0,0,0}, a1 = {0,0,0,0}, a2 = {0,0,0,0}, a3 = {0,0,0,0};
        #pragma unroll 4
        for (int i = 0; i < 32; i += 4) {
            float4 v0 = base[(size_t)(i + 0) * MM * 8];
            float4 v1 = base[(size_t)(i + 1) * MM * 8];
            float4 v2 = base[(size_t)(i + 2) * MM * 8];
            float4 v3 = base[(size_t)(i + 3) * MM * 8];
            a0.x += v0.x; a0.y += v0.y; a0.z += v0.z; a0.w += v0.w;
            a1.x += v1.x; a1.y += v1.y; a1.z += v1.z; a1.w += v1.w;
            a2.x += v2.x; a2.y += v2.y; a2.z += v2.z; a2.w += v2.w;
            a3.x += v3.x; a3.y += v3.y; a3.z += v3.z; a3.w += v3.w;
        }
        float4 a = {a0.x + a1.x + a2.x + a3.x, a0.y + a1.y + a2.y + a3.y,
                    a0.z + a1.z + a2.z + a3.z, a0.w + a1.w + a2.w + a3.w};
        int j = j0 + (t >> 3), d = (t & 7) * 4;
        float* dst = ws + WS_COLS + (n * MM + j) * DD + d;
        atomicAdd(dst + 0, a.x);
        atomicAdd(dst + 1, a.y);
        atomicAdd(dst + 2, a.z);
        atomicAdd(dst + 3, a.w);
    } else {
        for (int idx = t; idx < 15 * DD * SS; idx += 256) {
            int plane = idx >> 10;
            int ds = idx & 1023;
            ws[WS_CPACK + plane * (DD * SS) + ds] = coeffs[ds * 15 + plane];
        }
    }
}

// k_aux: RW[n,i,s], CWt[n,s,j], DW[n,i,s].  128 blocks; thread -> (n,m,s).
__global__ __launch_bounds__(256) void k_aux(const float* __restrict__ diag_bias,
                                             const float* __restrict__ all_bias,
                                             float* __restrict__ ws) {
    int idx = blockIdx.x * blockDim.x + threadIdx.x;   // over N*M*S
    int s = idx & 31;
    int nm = idx >> 5;                                  // n*M + m
    int n = nm >> 8;
    int m = nm & 255;
    const float inv_m = 1.0f / MM;
    const float inv_m2 = inv_m * inv_m;
    float u = 0.f, v = 0.f, dgacc = 0.f, w = 0.f;
    for (int d = 0; d < DD; ++d) {
        const float* cp = ws + WS_CPACK + d * SS + s;   // plane stride 1024
        float r = ws[WS_ROWS + nm * DD + d];
        float cl = ws[WS_COLS + nm * DD + d];
        float dv = ws[WS_DIAG + nm * DD + d];
        float sdv = ws[WS_SD + n * DD + d];
        float totv = ws[WS_TOT + n * DD + d];
        // i-dependent (all j): op6 cols_i/m, op7 rows_i/m, op12 diag_i
        u += cp[5 * 1024] * cl * inv_m + cp[6 * 1024] * r * inv_m + cp[11 * 1024] * dv;
        // j-dependent: op8 cols_j/m, op9 rows_j/m, op13 diag_j
        v += cp[7 * 1024] * cl * inv_m + cp[8 * 1024] * r * inv_m + cp[12 * 1024] * dv;
        // diagonal-only: op1..op5
        dgacc += cp[0] * dv + cp[1 * 1024] * sdv * inv_m + cp[2 * 1024] * r * inv_m
               + cp[3 * 1024] * cl * inv_m + cp[4 * 1024] * totv * inv_m2;
        // constant: op14 sd/m, op15 tot/m^2
        w += cp[13 * 1024] * sdv * inv_m + cp[14 * 1024] * totv * inv_m2;
    }
    ws[WS_RW + nm * SS + s] = u + w + all_bias[s];
    ws[WS_CWT + (n * SS + s) * MM + m] = v;
    ws[WS_DW + nm * SS + s] = dgacc + diag_bias[s];
}

// k_main: block per (n,i) row; 256 threads = j.  All global I/O coalesced via
// LDS tile (rows padded to 36 floats: 16B-aligned b128, bank floor only).
__global__ __launch_bounds__(256) void k_main(const float* __restrict__ in,
                                              const float* __restrict__ ws,
                                              float* __restrict__ out) {
    __shared__ float tile[256 * 36];
    int nm = blockIdx.x;              // n*M + i
    int n = nm >> 8;
    int i = nm & 255;
    int t = threadIdx.x;              // j

    // acc init: RW (wave-uniform -> s_load) + CWt (lane-contiguous)
    const float* rwp = ws + WS_RW + nm * SS;
    const float* cwt = ws + WS_CWT + n * SS * MM + t;
    float acc[SS];
    #pragma unroll
    for (int s = 0; s < SS; ++s) acc[s] = rwp[s] + cwt[s * MM];
    if (t == i) {
        const float4* dw = (const float4*)(ws + WS_DW + nm * SS);
        #pragma unroll
        for (int q = 0; q < 8; ++q) {
            float4 dq = dw[q];
            acc[q * 4 + 0] += dq.x;
            acc[q * 4 + 1] += dq.y;
            acc[q * 4 + 2] += dq.z;
            acc[q * 4 + 3] += dq.w;
        }
    }

    // phase 1: stage A-row in[n,i,:,:] (32KB contiguous)
    {
        const float4* Arow = (const float4*)(in + (size_t)nm * MM * DD);
        #pragma unroll
        for (int k = 0; k < 8; ++k) {
            int idx = t + k * 256;          // f4 index, 2048 total
            int p = idx >> 3, c = idx & 7;  // point, d4-slot
            float4 v = Arow[idx];
            *(float4*)(tile + p * 36 + c * 4) = v;
        }
    }
    __syncthreads();

    // phase 2: A-side FMAs (C10)
    const float* c10 = ws + WS_CPACK + 9 * (DD * SS);    // uniform -> s_load
    const float* c11 = ws + WS_CPACK + 10 * (DD * SS);
    const float* lrow = tile + t * 36;
    #pragma unroll
    for (int dq = 0; dq < 8; ++dq) {
        float4 a4 = *(const float4*)(lrow + dq * 4);
        const float* ca = c10 + dq * 4 * SS;
        #pragma unroll
        for (int r = 0; r < 4; ++r) {
            float a = (r == 0) ? a4.x : (r == 1) ? a4.y : (r == 2) ? a4.z : a4.w;
            #pragma unroll
            for (int s = 0; s < SS; ++s)
                acc[s] = fmaf(a, ca[r * SS + s], acc[s]);
        }
    }
    __syncthreads();

    // phase 3: stage B-row in[n,j,i,:] for all j (128B rows, 8-lane contiguous)
    {
        const float4* Bbase = (const float4*)in;
        #pragma unroll
        for (int k = 0; k < 8; ++k) {
            int idx = t + k * 256;
            int p = idx >> 3, c = idx & 7;
            float4 v = Bbase[((size_t)(n * MM + p) * MM + i) * 8 + c];
            *(float4*)(tile + p * 36 + c * 4) = v;
        }
    }
    __syncthreads();

    // phase 4: B-side FMAs (C11)
    #pragma unroll
    for (int dq = 0; dq < 8; ++dq) {
        float4 b4 = *(const float4*)(lrow + dq * 4);
        const float* cb = c11 + dq * 4 * SS;
        #pragma unroll
        for (int r = 0; r < 4; ++r) {
            float bb = (r == 0) ? b4.x : (r == 1) ? b4.y : (r == 2) ? b4.z : b4.w;
            #pragma unroll
            for (int s = 0; s < SS; ++s)
                acc[s] = fmaf(bb, cb[r * SS + s], acc[s]);
        }
    }
    // own-row reads done; safe to overwrite own row (others only read own rows)
    #pragma unroll
    for (int q = 0; q < 8; ++q)
        *(float4*)(tile + t * 36 + q * 4) =
            make_float4(acc[q * 4 + 0], acc[q * 4 + 1], acc[q * 4 + 2], acc[q * 4 + 3]);
    __syncthreads();

    // phase 6: coalesced store of out[n,i,:,:] (32KB contiguous)
    {
        float4* Orow = (float4*)(out + (size_t)nm * MM * SS);
        #pragma unroll
        for (int k = 0; k < 8; ++k) {
            int idx = t + k * 256;
            int p = idx >> 3, c = idx & 7;
            Orow[idx] = *(const float4*)(tile + p * 36 + c * 4);
        }
    }
}

extern "C" void kernel_launch(void* const* d_in, const int* in_sizes, int n_in,
                              void* d_out, int out_size, void* d_ws, size_t ws_size,
                              hipStream_t stream) {
    const float* in = (const float*)d_in[0];
    // d_in[1] = mask (all-ones, unused by the reference math)
    const float* coeffs = (const float*)d_in[2];
    const float* diag_bias = (const float*)d_in[3];
    const float* all_bias = (const float*)d_in[4];
    float* out = (float*)d_out;
    float* ws = (float*)d_ws;

    // zero atomic targets: cols + sd + tot (contiguous region at ws start)
    hipMemsetAsync(d_ws, 0, (size_t)(32768 + 256) * sizeof(float), stream);
    k_rows<<<NN * MM, 256, 0, stream>>>(in, ws);
    k_cols<<<257, 256, 0, stream>>>(in, coeffs, ws);
    k_aux<<<(NN * MM * SS) / 256, 256, 0, stream>>>(diag_bias, all_bias, ws);
    k_main<<<NN * MM, 256, 0, stream>>>(in, ws, out);
}